// Round 2
// baseline (1351.110 us; speedup 1.0000x reference)
//
#include <hip/hip_runtime.h>
#include <hip/hip_bf16.h>
#include <stdint.h>

#define FEAT   128
#define NOUT   384
#define NRBF   20
#define NNODES 20000
#define NEDGES 320000
#define CUTOFF_F 5.0f

typedef float f32x4 __attribute__((ext_vector_type(4)));
typedef float f32x2 __attribute__((ext_vector_type(2)));
typedef short bf16x8 __attribute__((ext_vector_type(8)));

static __device__ __forceinline__ short f2bf_rne(float x) {
    uint32_t u = __float_as_uint(x);
    uint32_t r = (u + 0x7fffu + ((u >> 16) & 1u)) >> 16;
    return (short)(uint16_t)r;
}
static __device__ __forceinline__ uint32_t pack2_bf16(float lo, float hi) {
    return (uint32_t)(uint16_t)f2bf_rne(lo) | ((uint32_t)(uint16_t)f2bf_rne(hi) << 16);
}
static __device__ __forceinline__ float bf16lo_to_f(uint32_t p) { return __uint_as_float(p << 16); }
static __device__ __forceinline__ float bf16hi_to_f(uint32_t p) { return __uint_as_float(p & 0xffff0000u); }

// dtype-polymorphic scalar/pair loads ----------------------------------------
template<bool BF> static __device__ __forceinline__ float ldf(const void* p, size_t i) {
    if constexpr (BF) return __uint_as_float((uint32_t)(((const uint16_t*)p)[i]) << 16);
    else              return ((const float*)p)[i];
}
template<bool BF> static __device__ __forceinline__ f32x2 ldf2(const void* p, size_t i) {
    if constexpr (BF) {
        uint32_t w = *(const uint32_t*)((const uint16_t*)p + i);
        f32x2 r; r.x = bf16lo_to_f(w); r.y = bf16hi_to_f(w); return r;
    } else return *(const f32x2*)((const float*)p + i);
}

// ---------------- Kernel 0: dtype probe -------------------------------------
__global__ void k_detect(const uint32_t* __restrict__ sj, uint32_t* __restrict__ flag) {
    const int lane = threadIdx.x & 63;
    const uint32_t w = sj[lane];
    const uint32_t e = (w >> 7) & 0xFFu;
    const unsigned long long m = __ballot(e >= 115u && e <= 135u);
    if (threadIdx.x == 0) *flag = (__popcll(m) >= 32) ? 1u : 0u;
}

// ---------------- Kernel 1: h = silu(s_j @ W1 + b1), h stored bf16 ----------
template<bool BF>
static __device__ __forceinline__ void mlp1_body(const void* __restrict__ sj,
                                                 const void* __restrict__ W1,
                                                 const void* __restrict__ b1,
                                                 short* __restrict__ h) {
    const int lane = threadIdx.x & 63;
    const int wv   = threadIdx.x >> 6;
    const int quad = lane >> 4;
    const int l15  = lane & 15;
    const int m0   = blockIdx.x * 64 + wv * 16;
    const int n0   = blockIdx.y * 16;
    const int row  = m0 + l15;
    const int col  = n0 + l15;

    f32x4 acc = {0.f, 0.f, 0.f, 0.f};
    #pragma unroll
    for (int kk = 0; kk < FEAT; kk += 32) {
        const int kbase = kk + quad * 8;
        bf16x8 af;
        if (row < NNODES) {
            if constexpr (BF) {
                af = *(const bf16x8*)((const short*)sj + (size_t)row * FEAT + kbase);
            } else {
                const float* ap = (const float*)sj + (size_t)row * FEAT + kbase;
                f32x4 a0 = *(const f32x4*)(ap);
                f32x4 a1 = *(const f32x4*)(ap + 4);
                af[0] = f2bf_rne(a0.x); af[1] = f2bf_rne(a0.y);
                af[2] = f2bf_rne(a0.z); af[3] = f2bf_rne(a0.w);
                af[4] = f2bf_rne(a1.x); af[5] = f2bf_rne(a1.y);
                af[6] = f2bf_rne(a1.z); af[7] = f2bf_rne(a1.w);
            }
        } else {
            #pragma unroll
            for (int j = 0; j < 8; j++) af[j] = 0;
        }
        bf16x8 bfv;
        #pragma unroll
        for (int j = 0; j < 8; j++) {
            if constexpr (BF) bfv[j] = ((const short*)W1)[(size_t)(kbase + j) * FEAT + col];
            else              bfv[j] = f2bf_rne(((const float*)W1)[(size_t)(kbase + j) * FEAT + col]);
        }
        acc = __builtin_amdgcn_mfma_f32_16x16x32_bf16(af, bfv, acc, 0, 0, 0);
    }

    const float bias = ldf<BF>(b1, col);
    #pragma unroll
    for (int r = 0; r < 4; r++) {
        const int orow = m0 + quad * 4 + r;
        if (orow < NNODES) {
            float v = acc[r] + bias;
            float s = v * __frcp_rn(1.0f + __expf(-v));   // silu
            h[(size_t)orow * FEAT + col] = f2bf_rne(s);
        }
    }
}

__global__ __launch_bounds__(256) void k_mlp1(const void* sj, const void* W1,
                                              const void* b1, short* h,
                                              const uint32_t* __restrict__ flag) {
    if (*flag) mlp1_body<true>(sj, W1, b1, h);
    else       mlp1_body<false>(sj, W1, b1, h);
}

// ---------------- Kernel 2: inv = h @ W2 + b2, inv stored bf16 ---------------
template<bool BF>
static __device__ __forceinline__ void mlp2_body(const short* __restrict__ h,
                                                 const void* __restrict__ W2,
                                                 const void* __restrict__ b2,
                                                 short* __restrict__ inv) {
    const int lane = threadIdx.x & 63;
    const int wv   = threadIdx.x >> 6;
    const int quad = lane >> 4;
    const int l15  = lane & 15;
    const int m0   = blockIdx.x * 64 + wv * 16;
    const int n0   = blockIdx.y * 16;
    const int row  = m0 + l15;
    const int col  = n0 + l15;

    f32x4 acc = {0.f, 0.f, 0.f, 0.f};
    #pragma unroll
    for (int kk = 0; kk < FEAT; kk += 32) {
        const int kbase = kk + quad * 8;
        bf16x8 af;
        if (row < NNODES) {
            af = *(const bf16x8*)(h + (size_t)row * FEAT + kbase);
        } else {
            #pragma unroll
            for (int j = 0; j < 8; j++) af[j] = 0;
        }
        bf16x8 bfv;
        #pragma unroll
        for (int j = 0; j < 8; j++) {
            if constexpr (BF) bfv[j] = ((const short*)W2)[(size_t)(kbase + j) * NOUT + col];
            else              bfv[j] = f2bf_rne(((const float*)W2)[(size_t)(kbase + j) * NOUT + col]);
        }
        acc = __builtin_amdgcn_mfma_f32_16x16x32_bf16(af, bfv, acc, 0, 0, 0);
    }

    const float bias = ldf<BF>(b2, col);
    #pragma unroll
    for (int r = 0; r < 4; r++) {
        const int orow = m0 + quad * 4 + r;
        if (orow < NNODES) {
            inv[(size_t)orow * NOUT + col] = f2bf_rne(acc[r] + bias);
        }
    }
}

__global__ __launch_bounds__(256) void k_mlp2(const short* h, const void* W2,
                                              const void* b2, short* inv,
                                              const uint32_t* __restrict__ flag) {
    if (*flag) mlp2_body<true>(h, W2, b2, inv);
    else       mlp2_body<false>(h, W2, b2, inv);
}

// ---------------- Kernel 3: edge kernel v2 ----------------------------------
// Wr/br live in LDS (frees ~126 VGPRs -> 4 waves/SIMD). Each wave processes 4
// consecutive edges per iteration: 12 gather loads in flight, coalesced
// nbrs/dist reads, 6 KB contiguous nontemporal stores. ds_read_b64 of Wr is
// 2-way bank aliased = free. Gathers stay L2/LLC-resident because output
// stores are nontemporal (no L2 allocation).
#define E_PER 4

template<bool BF>
static __device__ __forceinline__ void edge_body(const void* __restrict__ dist,
                                                 const int* __restrict__ nbrs,
                                                 const short* __restrict__ inv,
                                                 void* __restrict__ out,
                                                 int total_waves,
                                                 const float* __restrict__ sm_wr,
                                                 const float* __restrict__ sm_br) {
    const int lane = threadIdx.x & 63;
    const int wgid = blockIdx.x * (blockDim.x >> 6) + (threadIdx.x >> 6);
    const float A_COEF = 0.628318530717958647692f;  // pi / 5

    // per-lane bias columns -> registers (6 VGPRs)
    f32x2 brv[3];
    #pragma unroll
    for (int k = 0; k < 3; k++)
        brv[k] = *(const f32x2*)(sm_br + 2 * lane + 128 * k);

    const int stride = total_waves * E_PER;
    for (int e0 = wgid * E_PER; e0 < NEDGES; e0 += stride) {
        // ---- coalesced nbrs/dist for 4 consecutive edges (wave-uniform) ----
        int   jj[E_PER];
        float dd[E_PER];
        #pragma unroll
        for (int k = 0; k < E_PER; k++) {
            int j = nbrs[2 * (size_t)(e0 + k) + 1];
            jj[k] = min(max(j, 0), NNODES - 1);
            dd[k] = ldf<BF>(dist, e0 + k);
        }

        // ---- 12 gather loads issued up front (hidden under rbf compute) ----
        uint32_t p[E_PER][3];
        #pragma unroll
        for (int k = 0; k < E_PER; k++) {
            const uint32_t* ip = (const uint32_t*)inv + (size_t)jj[k] * (NOUT / 2) + lane;
            p[k][0] = ip[0];
            p[k][1] = ip[64];
            p[k][2] = ip[128];
        }

        // ---- per-edge trig state ----
        float sc[E_PER], sp[E_PER], c2[E_PER], env[E_PER], uu[E_PER];
        #pragma unroll
        for (int k = 0; k < E_PER; k++) {
            float s, c;
            __sincosf(dd[k] * A_COEF, &s, &c);
            env[k] = (dd[k] < CUTOFF_F) ? (0.5f * (c + 1.0f)) : 0.0f;
            uu[k]  = __fdividef(env[k], dd[k]);
            c2[k]  = 2.0f * c;
            sp[k]  = 0.0f;
            sc[k]  = s;
        }

        f32x2 acc[E_PER][3];
        #pragma unroll
        for (int k = 0; k < E_PER; k++) {
            #pragma unroll
            for (int c = 0; c < 3; c++) { acc[k][c].x = 0.f; acc[k][c].y = 0.f; }
        }

        // ---- rbf dot: 3 ds_read_b64 amortized over 4 edges (12 pk_fma) ----
        #pragma unroll
        for (int n = 0; n < NRBF; n++) {
            const float* wp = sm_wr + n * NOUT + 2 * lane;
            const f32x2 w0 = *(const f32x2*)(wp);
            const f32x2 w1 = *(const f32x2*)(wp + 128);
            const f32x2 w2 = *(const f32x2*)(wp + 256);
            #pragma unroll
            for (int k = 0; k < E_PER; k++) {
                acc[k][0] += sc[k] * w0;
                acc[k][1] += sc[k] * w1;
                acc[k][2] += sc[k] * w2;
                const float sn = __builtin_fmaf(c2[k], sc[k], -sp[k]);
                sp[k] = sc[k]; sc[k] = sn;
            }
        }

        // ---- epilogue: fold env/u, multiply gathered phi, stream out -------
        #pragma unroll
        for (int k = 0; k < E_PER; k++) {
            const f32x2 w0 = acc[k][0] * uu[k] + brv[0] * env[k];
            const f32x2 w1 = acc[k][1] * uu[k] + brv[1] * env[k];
            const f32x2 w2 = acc[k][2] * uu[k] + brv[2] * env[k];

            const float o0x = bf16lo_to_f(p[k][0]) * w0.x, o0y = bf16hi_to_f(p[k][0]) * w0.y;
            const float o1x = bf16lo_to_f(p[k][1]) * w1.x, o1y = bf16hi_to_f(p[k][1]) * w1.y;
            const float o2x = bf16lo_to_f(p[k][2]) * w2.x, o2y = bf16hi_to_f(p[k][2]) * w2.y;

            if constexpr (BF) {
                uint32_t* op = (uint32_t*)out + (size_t)(e0 + k) * (NOUT / 2) + lane;
                __builtin_nontemporal_store(pack2_bf16(o0x, o0y), op);
                __builtin_nontemporal_store(pack2_bf16(o1x, o1y), op + 64);
                __builtin_nontemporal_store(pack2_bf16(o2x, o2y), op + 128);
            } else {
                float* op = (float*)out + (size_t)(e0 + k) * NOUT + 2 * lane;
                f32x2 v0; v0.x = o0x; v0.y = o0y;
                f32x2 v1; v1.x = o1x; v1.y = o1y;
                f32x2 v2; v2.x = o2x; v2.y = o2y;
                __builtin_nontemporal_store(v0, (f32x2*)(op));
                __builtin_nontemporal_store(v1, (f32x2*)(op + 128));
                __builtin_nontemporal_store(v2, (f32x2*)(op + 256));
            }
        }
    }
}

__global__ __launch_bounds__(256, 4) void k_edge(const void* dist, const int* nbrs,
                                                 const void* Wr, const void* brp,
                                                 const short* inv, void* out,
                                                 int total_waves,
                                                 const uint32_t* __restrict__ flag) {
    __shared__ float smem[NRBF * NOUT + NOUT];   // 32,256 B -> 4 blocks/CU
    const int t = threadIdx.x;
    const uint32_t fl = *flag;
    if (fl) {
        for (int i = t; i < NRBF * NOUT; i += 256) smem[i] = ldf<true>(Wr, i);
        for (int i = t; i < NOUT; i += 256)        smem[NRBF * NOUT + i] = ldf<true>(brp, i);
    } else {
        for (int i = t; i < NRBF * NOUT; i += 256) smem[i] = ldf<false>(Wr, i);
        for (int i = t; i < NOUT; i += 256)        smem[NRBF * NOUT + i] = ldf<false>(brp, i);
    }
    __syncthreads();
    if (fl) edge_body<true>(dist, nbrs, inv, out, total_waves, smem, smem + NRBF * NOUT);
    else    edge_body<false>(dist, nbrs, inv, out, total_waves, smem, smem + NRBF * NOUT);
}

extern "C" void kernel_launch(void* const* d_in, const int* in_sizes, int n_in,
                              void* d_out, int out_size, void* d_ws, size_t ws_size,
                              hipStream_t stream) {
    const void* s_j  = d_in[0];
    const void* dist = d_in[1];
    const int*  nbrs = (const int*)d_in[2];
    const void* W1   = d_in[3];
    const void* b1   = d_in[4];
    const void* W2   = d_in[5];
    const void* b2   = d_in[6];
    const void* Wr   = d_in[7];
    const void* br   = d_in[8];

    uint32_t* flag = (uint32_t*)d_ws;                       // 4 B (+pad to 256 B)
    short* h   = (short*)d_ws + 128;                        // 20000*128 bf16 = 5.12 MB
    short* inv = h + (size_t)NNODES * FEAT;                 // 20000*384 bf16 = 15.36 MB

    dim3 blk(256);
    k_detect<<<dim3(1), dim3(64), 0, stream>>>((const uint32_t*)s_j, flag);
    k_mlp1<<<dim3(313, FEAT / 16), blk, 0, stream>>>(s_j, W1, b1, h, flag);
    k_mlp2<<<dim3(313, NOUT / 16), blk, 0, stream>>>(h, W2, b2, inv, flag);

    const int blocks = 2048;                                 // 8192 waves
    const int total_waves = blocks * (256 / 64);
    k_edge<<<dim3(blocks), blk, 0, stream>>>(dist, nbrs, Wr, br, inv, d_out,
                                             total_waves, flag);
}

// Round 3
// 649.380 us; speedup vs baseline: 2.0806x; 2.0806x over previous
//
#include <hip/hip_runtime.h>
#include <hip/hip_bf16.h>
#include <stdint.h>

#define FEAT   128
#define NOUT   384
#define NRBF   20
#define NNODES 20000
#define NEDGES 320000
#define CUTOFF_F 5.0f

typedef float f32x4 __attribute__((ext_vector_type(4)));
typedef float f32x2 __attribute__((ext_vector_type(2)));
typedef short bf16x8 __attribute__((ext_vector_type(8)));

static __device__ __forceinline__ short f2bf_rne(float x) {
    uint32_t u = __float_as_uint(x);
    uint32_t r = (u + 0x7fffu + ((u >> 16) & 1u)) >> 16;
    return (short)(uint16_t)r;
}
static __device__ __forceinline__ uint32_t pack2_bf16(float lo, float hi) {
    return (uint32_t)(uint16_t)f2bf_rne(lo) | ((uint32_t)(uint16_t)f2bf_rne(hi) << 16);
}
static __device__ __forceinline__ float bf16lo_to_f(uint32_t p) { return __uint_as_float(p << 16); }
static __device__ __forceinline__ float bf16hi_to_f(uint32_t p) { return __uint_as_float(p & 0xffff0000u); }

// dtype-polymorphic scalar/pair loads ----------------------------------------
template<bool BF> static __device__ __forceinline__ float ldf(const void* p, size_t i) {
    if constexpr (BF) return __uint_as_float((uint32_t)(((const uint16_t*)p)[i]) << 16);
    else              return ((const float*)p)[i];
}
template<bool BF> static __device__ __forceinline__ f32x2 ldf2(const void* p, size_t i) {
    if constexpr (BF) {
        uint32_t w = *(const uint32_t*)((const uint16_t*)p + i);
        f32x2 r; r.x = bf16lo_to_f(w); r.y = bf16hi_to_f(w); return r;
    } else return *(const f32x2*)((const float*)p + i);
}

// ---------------- Kernel 0: dtype probe -------------------------------------
__global__ void k_detect(const uint32_t* __restrict__ sj, uint32_t* __restrict__ flag) {
    const int lane = threadIdx.x & 63;
    const uint32_t w = sj[lane];
    const uint32_t e = (w >> 7) & 0xFFu;
    const unsigned long long m = __ballot(e >= 115u && e <= 135u);
    if (threadIdx.x == 0) *flag = (__popcll(m) >= 32) ? 1u : 0u;
}

// ---------------- Kernel 1: h = silu(s_j @ W1 + b1), h stored bf16 ----------
template<bool BF>
static __device__ __forceinline__ void mlp1_body(const void* __restrict__ sj,
                                                 const void* __restrict__ W1,
                                                 const void* __restrict__ b1,
                                                 short* __restrict__ h) {
    const int lane = threadIdx.x & 63;
    const int wv   = threadIdx.x >> 6;
    const int quad = lane >> 4;
    const int l15  = lane & 15;
    const int m0   = blockIdx.x * 64 + wv * 16;
    const int n0   = blockIdx.y * 16;
    const int row  = m0 + l15;
    const int col  = n0 + l15;

    f32x4 acc = {0.f, 0.f, 0.f, 0.f};
    #pragma unroll
    for (int kk = 0; kk < FEAT; kk += 32) {
        const int kbase = kk + quad * 8;
        bf16x8 af;
        if (row < NNODES) {
            if constexpr (BF) {
                af = *(const bf16x8*)((const short*)sj + (size_t)row * FEAT + kbase);
            } else {
                const float* ap = (const float*)sj + (size_t)row * FEAT + kbase;
                f32x4 a0 = *(const f32x4*)(ap);
                f32x4 a1 = *(const f32x4*)(ap + 4);
                af[0] = f2bf_rne(a0.x); af[1] = f2bf_rne(a0.y);
                af[2] = f2bf_rne(a0.z); af[3] = f2bf_rne(a0.w);
                af[4] = f2bf_rne(a1.x); af[5] = f2bf_rne(a1.y);
                af[6] = f2bf_rne(a1.z); af[7] = f2bf_rne(a1.w);
            }
        } else {
            #pragma unroll
            for (int j = 0; j < 8; j++) af[j] = 0;
        }
        bf16x8 bfv;
        #pragma unroll
        for (int j = 0; j < 8; j++) {
            if constexpr (BF) bfv[j] = ((const short*)W1)[(size_t)(kbase + j) * FEAT + col];
            else              bfv[j] = f2bf_rne(((const float*)W1)[(size_t)(kbase + j) * FEAT + col]);
        }
        acc = __builtin_amdgcn_mfma_f32_16x16x32_bf16(af, bfv, acc, 0, 0, 0);
    }

    const float bias = ldf<BF>(b1, col);
    #pragma unroll
    for (int r = 0; r < 4; r++) {
        const int orow = m0 + quad * 4 + r;
        if (orow < NNODES) {
            float v = acc[r] + bias;
            float s = v * __frcp_rn(1.0f + __expf(-v));   // silu
            h[(size_t)orow * FEAT + col] = f2bf_rne(s);
        }
    }
}

__global__ __launch_bounds__(256) void k_mlp1(const void* sj, const void* W1,
                                              const void* b1, short* h,
                                              const uint32_t* __restrict__ flag) {
    if (*flag) mlp1_body<true>(sj, W1, b1, h);
    else       mlp1_body<false>(sj, W1, b1, h);
}

// ---------------- Kernel 2: inv = h @ W2 + b2, inv stored bf16 ---------------
template<bool BF>
static __device__ __forceinline__ void mlp2_body(const short* __restrict__ h,
                                                 const void* __restrict__ W2,
                                                 const void* __restrict__ b2,
                                                 short* __restrict__ inv) {
    const int lane = threadIdx.x & 63;
    const int wv   = threadIdx.x >> 6;
    const int quad = lane >> 4;
    const int l15  = lane & 15;
    const int m0   = blockIdx.x * 64 + wv * 16;
    const int n0   = blockIdx.y * 16;
    const int row  = m0 + l15;
    const int col  = n0 + l15;

    f32x4 acc = {0.f, 0.f, 0.f, 0.f};
    #pragma unroll
    for (int kk = 0; kk < FEAT; kk += 32) {
        const int kbase = kk + quad * 8;
        bf16x8 af;
        if (row < NNODES) {
            af = *(const bf16x8*)(h + (size_t)row * FEAT + kbase);
        } else {
            #pragma unroll
            for (int j = 0; j < 8; j++) af[j] = 0;
        }
        bf16x8 bfv;
        #pragma unroll
        for (int j = 0; j < 8; j++) {
            if constexpr (BF) bfv[j] = ((const short*)W2)[(size_t)(kbase + j) * NOUT + col];
            else              bfv[j] = f2bf_rne(((const float*)W2)[(size_t)(kbase + j) * NOUT + col]);
        }
        acc = __builtin_amdgcn_mfma_f32_16x16x32_bf16(af, bfv, acc, 0, 0, 0);
    }

    const float bias = ldf<BF>(b2, col);
    #pragma unroll
    for (int r = 0; r < 4; r++) {
        const int orow = m0 + quad * 4 + r;
        if (orow < NNODES) {
            inv[(size_t)orow * NOUT + col] = f2bf_rne(acc[r] + bias);
        }
    }
}

__global__ __launch_bounds__(256) void k_mlp2(const short* h, const void* W2,
                                              const void* b2, short* inv,
                                              const uint32_t* __restrict__ flag) {
    if (*flag) mlp2_body<true>(h, W2, b2, inv);
    else       mlp2_body<false>(h, W2, b2, inv);
}

// ---------------- Kernel 3: edge kernel v3 ----------------------------------
// Round-0 structure (1 edge per wave-iteration, plain cached stores, no
// launch-bounds wave clamp) + ONE change kept from v2: Wr/br staged in LDS
// instead of 120 VGPRs of per-lane registers. v2's E_PER=4 + nontemporal
// stores + (256,4) clamp quintupled TCC traffic (FETCH 2.68 GB / WRITE
// 1.30 GB vs ~0.75 GB ideal) and tripled k_edge time — reverted.
template<bool BF>
static __device__ __forceinline__ void edge_body(const void* __restrict__ dist,
                                                 const int* __restrict__ nbrs,
                                                 const short* __restrict__ inv,
                                                 void* __restrict__ out,
                                                 int total_waves,
                                                 const float* __restrict__ sm_wr,
                                                 const float* __restrict__ sm_br) {
    const int lane = threadIdx.x & 63;
    const int wgid = blockIdx.x * (blockDim.x >> 6) + (threadIdx.x >> 6);
    const float A_COEF = 0.628318530717958647692f;  // pi / 5

    // per-lane bias columns -> 6 VGPRs
    f32x2 brv[3];
    #pragma unroll
    for (int k = 0; k < 3; k++)
        brv[k] = *(const f32x2*)(sm_br + 2 * lane + 128 * k);

    for (int e = wgid; e < NEDGES; e += total_waves) {
        int j = nbrs[2 * (size_t)e + 1];
        j = min(max(j, 0), NNODES - 1);
        const float d = ldf<BF>(dist, e);

        // gather loads issued early (3 outstanding, hidden under rbf compute)
        const uint32_t* invp = (const uint32_t*)(inv) + (size_t)j * (NOUT / 2) + lane;
        const uint32_t p0 = invp[0];
        const uint32_t p1 = invp[64];
        const uint32_t p2 = invp[128];

        const float a = d * A_COEF;
        float s, c;
        __sincosf(a, &s, &c);
        const float env = (d < CUTOFF_F) ? (0.5f * (c + 1.0f)) : 0.0f;
        const float u   = __fdividef(env, d);
        const float c2  = 2.0f * c;

        f32x2 acc0 = {0.f, 0.f}, acc1 = {0.f, 0.f}, acc2 = {0.f, 0.f};
        float sp = 0.0f, sc = s;
        #pragma unroll
        for (int n = 0; n < NRBF; n++) {
            const float* wp = sm_wr + n * NOUT + 2 * lane;
            const f32x2 w0 = *(const f32x2*)(wp);
            const f32x2 w1 = *(const f32x2*)(wp + 128);
            const f32x2 w2 = *(const f32x2*)(wp + 256);
            acc0 += sc * w0;
            acc1 += sc * w1;
            acc2 += sc * w2;
            const float sn = __builtin_fmaf(c2, sc, -sp);
            sp = sc; sc = sn;
        }

        f32x2 w0 = acc0 * u + brv[0] * env;
        f32x2 w1 = acc1 * u + brv[1] * env;
        f32x2 w2 = acc2 * u + brv[2] * env;

        const float o0x = bf16lo_to_f(p0) * w0.x, o0y = bf16hi_to_f(p0) * w0.y;
        const float o1x = bf16lo_to_f(p1) * w1.x, o1y = bf16hi_to_f(p1) * w1.y;
        const float o2x = bf16lo_to_f(p2) * w2.x, o2y = bf16hi_to_f(p2) * w2.y;

        if constexpr (BF) {
            uint32_t* op = (uint32_t*)out + (size_t)e * (NOUT / 2) + lane;
            op[0]   = pack2_bf16(o0x, o0y);
            op[64]  = pack2_bf16(o1x, o1y);
            op[128] = pack2_bf16(o2x, o2y);
        } else {
            float* op = (float*)out + (size_t)e * NOUT + 2 * lane;
            f32x2 v0; v0.x = o0x; v0.y = o0y;
            f32x2 v1; v1.x = o1x; v1.y = o1y;
            f32x2 v2; v2.x = o2x; v2.y = o2y;
            *(f32x2*)(op)       = v0;
            *(f32x2*)(op + 128) = v1;
            *(f32x2*)(op + 256) = v2;
        }
    }
}

__global__ __launch_bounds__(256) void k_edge(const void* dist, const int* nbrs,
                                              const void* Wr, const void* brp,
                                              const short* inv, void* out,
                                              int total_waves,
                                              const uint32_t* __restrict__ flag) {
    __shared__ float smem[NRBF * NOUT + NOUT];   // 32,256 B
    const int t = threadIdx.x;
    const uint32_t fl = *flag;
    if (fl) {
        for (int i = t; i < NRBF * NOUT; i += 256) smem[i] = ldf<true>(Wr, i);
        for (int i = t; i < NOUT; i += 256)        smem[NRBF * NOUT + i] = ldf<true>(brp, i);
    } else {
        for (int i = t; i < NRBF * NOUT; i += 256) smem[i] = ldf<false>(Wr, i);
        for (int i = t; i < NOUT; i += 256)        smem[NRBF * NOUT + i] = ldf<false>(brp, i);
    }
    __syncthreads();
    if (fl) edge_body<true>(dist, nbrs, inv, out, total_waves, smem, smem + NRBF * NOUT);
    else    edge_body<false>(dist, nbrs, inv, out, total_waves, smem, smem + NRBF * NOUT);
}

extern "C" void kernel_launch(void* const* d_in, const int* in_sizes, int n_in,
                              void* d_out, int out_size, void* d_ws, size_t ws_size,
                              hipStream_t stream) {
    const void* s_j  = d_in[0];
    const void* dist = d_in[1];
    const int*  nbrs = (const int*)d_in[2];
    const void* W1   = d_in[3];
    const void* b1   = d_in[4];
    const void* W2   = d_in[5];
    const void* b2   = d_in[6];
    const void* Wr   = d_in[7];
    const void* br   = d_in[8];

    uint32_t* flag = (uint32_t*)d_ws;                       // 4 B (+pad to 256 B)
    short* h   = (short*)d_ws + 128;                        // 20000*128 bf16 = 5.12 MB
    short* inv = h + (size_t)NNODES * FEAT;                 // 20000*384 bf16 = 15.36 MB

    dim3 blk(256);
    k_detect<<<dim3(1), dim3(64), 0, stream>>>((const uint32_t*)s_j, flag);
    k_mlp1<<<dim3(313, FEAT / 16), blk, 0, stream>>>(s_j, W1, b1, h, flag);
    k_mlp2<<<dim3(313, NOUT / 16), blk, 0, stream>>>(h, W2, b2, inv, flag);

    const int blocks = 2048;                                 // 8192 waves
    const int total_waves = blocks * (256 / 64);
    k_edge<<<dim3(blocks), blk, 0, stream>>>(dist, nbrs, Wr, br, inv, d_out,
                                             total_waves, flag);
}

// Round 4
// 607.418 us; speedup vs baseline: 2.2243x; 1.0691x over previous
//
#include <hip/hip_runtime.h>
#include <hip/hip_bf16.h>
#include <stdint.h>

#define FEAT   128
#define NOUT   384
#define NRBF   20
#define NNODES 20000
#define NEDGES 320000
#define CUTOFF_F 5.0f

typedef float f32x4 __attribute__((ext_vector_type(4)));
typedef float f32x2 __attribute__((ext_vector_type(2)));
typedef short bf16x8 __attribute__((ext_vector_type(8)));

static __device__ __forceinline__ short f2bf_rne(float x) {
    uint32_t u = __float_as_uint(x);
    uint32_t r = (u + 0x7fffu + ((u >> 16) & 1u)) >> 16;
    return (short)(uint16_t)r;
}
static __device__ __forceinline__ uint32_t pack2_bf16(float lo, float hi) {
    return (uint32_t)(uint16_t)f2bf_rne(lo) | ((uint32_t)(uint16_t)f2bf_rne(hi) << 16);
}
static __device__ __forceinline__ float bf16lo_to_f(uint32_t p) { return __uint_as_float(p << 16); }
static __device__ __forceinline__ float bf16hi_to_f(uint32_t p) { return __uint_as_float(p & 0xffff0000u); }

// dtype-polymorphic scalar/pair loads ----------------------------------------
template<bool BF> static __device__ __forceinline__ float ldf(const void* p, size_t i) {
    if constexpr (BF) return __uint_as_float((uint32_t)(((const uint16_t*)p)[i]) << 16);
    else              return ((const float*)p)[i];
}
template<bool BF> static __device__ __forceinline__ f32x2 ldf2(const void* p, size_t i) {
    if constexpr (BF) {
        uint32_t w = *(const uint32_t*)((const uint16_t*)p + i);
        f32x2 r; r.x = bf16lo_to_f(w); r.y = bf16hi_to_f(w); return r;
    } else return *(const f32x2*)((const float*)p + i);
}

// ---------------- Kernel 0: dtype probe -------------------------------------
__global__ void k_detect(const uint32_t* __restrict__ sj, uint32_t* __restrict__ flag) {
    const int lane = threadIdx.x & 63;
    const uint32_t w = sj[lane];
    const uint32_t e = (w >> 7) & 0xFFu;
    const unsigned long long m = __ballot(e >= 115u && e <= 135u);
    if (threadIdx.x == 0) *flag = (__popcll(m) >= 32) ? 1u : 0u;
}

// ---------------- Kernel 1: h = silu(s_j @ W1 + b1), h stored bf16 ----------
template<bool BF>
static __device__ __forceinline__ void mlp1_body(const void* __restrict__ sj,
                                                 const void* __restrict__ W1,
                                                 const void* __restrict__ b1,
                                                 short* __restrict__ h) {
    const int lane = threadIdx.x & 63;
    const int wv   = threadIdx.x >> 6;
    const int quad = lane >> 4;
    const int l15  = lane & 15;
    const int m0   = blockIdx.x * 64 + wv * 16;
    const int n0   = blockIdx.y * 16;
    const int row  = m0 + l15;
    const int col  = n0 + l15;

    f32x4 acc = {0.f, 0.f, 0.f, 0.f};
    #pragma unroll
    for (int kk = 0; kk < FEAT; kk += 32) {
        const int kbase = kk + quad * 8;
        bf16x8 af;
        if (row < NNODES) {
            if constexpr (BF) {
                af = *(const bf16x8*)((const short*)sj + (size_t)row * FEAT + kbase);
            } else {
                const float* ap = (const float*)sj + (size_t)row * FEAT + kbase;
                f32x4 a0 = *(const f32x4*)(ap);
                f32x4 a1 = *(const f32x4*)(ap + 4);
                af[0] = f2bf_rne(a0.x); af[1] = f2bf_rne(a0.y);
                af[2] = f2bf_rne(a0.z); af[3] = f2bf_rne(a0.w);
                af[4] = f2bf_rne(a1.x); af[5] = f2bf_rne(a1.y);
                af[6] = f2bf_rne(a1.z); af[7] = f2bf_rne(a1.w);
            }
        } else {
            #pragma unroll
            for (int j = 0; j < 8; j++) af[j] = 0;
        }
        bf16x8 bfv;
        #pragma unroll
        for (int j = 0; j < 8; j++) {
            if constexpr (BF) bfv[j] = ((const short*)W1)[(size_t)(kbase + j) * FEAT + col];
            else              bfv[j] = f2bf_rne(((const float*)W1)[(size_t)(kbase + j) * FEAT + col]);
        }
        acc = __builtin_amdgcn_mfma_f32_16x16x32_bf16(af, bfv, acc, 0, 0, 0);
    }

    const float bias = ldf<BF>(b1, col);
    #pragma unroll
    for (int r = 0; r < 4; r++) {
        const int orow = m0 + quad * 4 + r;
        if (orow < NNODES) {
            float v = acc[r] + bias;
            float s = v * __frcp_rn(1.0f + __expf(-v));   // silu
            h[(size_t)orow * FEAT + col] = f2bf_rne(s);
        }
    }
}

__global__ __launch_bounds__(256) void k_mlp1(const void* sj, const void* W1,
                                              const void* b1, short* h,
                                              const uint32_t* __restrict__ flag) {
    if (*flag) mlp1_body<true>(sj, W1, b1, h);
    else       mlp1_body<false>(sj, W1, b1, h);
}

// ---------------- Kernel 2: inv = h @ W2 + b2, inv stored bf16 ---------------
template<bool BF>
static __device__ __forceinline__ void mlp2_body(const short* __restrict__ h,
                                                 const void* __restrict__ W2,
                                                 const void* __restrict__ b2,
                                                 short* __restrict__ inv) {
    const int lane = threadIdx.x & 63;
    const int wv   = threadIdx.x >> 6;
    const int quad = lane >> 4;
    const int l15  = lane & 15;
    const int m0   = blockIdx.x * 64 + wv * 16;
    const int n0   = blockIdx.y * 16;
    const int row  = m0 + l15;
    const int col  = n0 + l15;

    f32x4 acc = {0.f, 0.f, 0.f, 0.f};
    #pragma unroll
    for (int kk = 0; kk < FEAT; kk += 32) {
        const int kbase = kk + quad * 8;
        bf16x8 af;
        if (row < NNODES) {
            af = *(const bf16x8*)(h + (size_t)row * FEAT + kbase);
        } else {
            #pragma unroll
            for (int j = 0; j < 8; j++) af[j] = 0;
        }
        bf16x8 bfv;
        #pragma unroll
        for (int j = 0; j < 8; j++) {
            if constexpr (BF) bfv[j] = ((const short*)W2)[(size_t)(kbase + j) * NOUT + col];
            else              bfv[j] = f2bf_rne(((const float*)W2)[(size_t)(kbase + j) * NOUT + col]);
        }
        acc = __builtin_amdgcn_mfma_f32_16x16x32_bf16(af, bfv, acc, 0, 0, 0);
    }

    const float bias = ldf<BF>(b2, col);
    #pragma unroll
    for (int r = 0; r < 4; r++) {
        const int orow = m0 + quad * 4 + r;
        if (orow < NNODES) {
            inv[(size_t)orow * NOUT + col] = f2bf_rne(acc[r] + bias);
        }
    }
}

__global__ __launch_bounds__(256) void k_mlp2(const short* h, const void* W2,
                                              const void* b2, short* inv,
                                              const uint32_t* __restrict__ flag) {
    if (*flag) mlp2_body<true>(h, W2, b2, inv);
    else       mlp2_body<false>(h, W2, b2, inv);
}

// ---------------- Kernel 3: edge kernel v4 ----------------------------------
// v3 (Wr/br in LDS, plain cached stores) + E_PER=4 edge batching to amortize
// the 30 KB/edge LDS read of Wr across 4 edges and keep 12 gather loads in
// flight. v2's regression is attributed to nontemporal partial-line stores
// (write/RMW amplification: WRITE 2.6x, FETCH ~10x) and the (256,4) VGPR
// clamp — BOTH omitted here. Plain stores, no launch-bounds min-wave clamp.
#define E_PER 4

template<bool BF>
static __device__ __forceinline__ void edge_body(const void* __restrict__ dist,
                                                 const int* __restrict__ nbrs,
                                                 const short* __restrict__ inv,
                                                 void* __restrict__ out,
                                                 int total_waves,
                                                 const float* __restrict__ sm_wr,
                                                 const float* __restrict__ sm_br) {
    const int lane = threadIdx.x & 63;
    const int wgid = blockIdx.x * (blockDim.x >> 6) + (threadIdx.x >> 6);
    const float A_COEF = 0.628318530717958647692f;  // pi / 5

    // per-lane bias columns -> 6 VGPRs
    f32x2 brv[3];
    #pragma unroll
    for (int k = 0; k < 3; k++)
        brv[k] = *(const f32x2*)(sm_br + 2 * lane + 128 * k);

    const int stride = total_waves * E_PER;
    for (int e0 = wgid * E_PER; e0 < NEDGES; e0 += stride) {
        // NEDGES % E_PER == 0 and e0 is a multiple of E_PER -> no tail check.
        int   jj[E_PER];
        float dd[E_PER];
        #pragma unroll
        for (int k = 0; k < E_PER; k++) {
            int j = nbrs[2 * (size_t)(e0 + k) + 1];
            jj[k] = min(max(j, 0), NNODES - 1);
            dd[k] = ldf<BF>(dist, e0 + k);
        }

        // 12 gather loads issued up front; results consumed only in epilogue.
        uint32_t p[E_PER][3];
        #pragma unroll
        for (int k = 0; k < E_PER; k++) {
            const uint32_t* ip = (const uint32_t*)inv + (size_t)jj[k] * (NOUT / 2) + lane;
            p[k][0] = ip[0];
            p[k][1] = ip[64];
            p[k][2] = ip[128];
        }

        float sc[E_PER], sp[E_PER], c2[E_PER], env[E_PER], uu[E_PER];
        #pragma unroll
        for (int k = 0; k < E_PER; k++) {
            float s, c;
            __sincosf(dd[k] * A_COEF, &s, &c);
            env[k] = (dd[k] < CUTOFF_F) ? (0.5f * (c + 1.0f)) : 0.0f;
            uu[k]  = __fdividef(env[k], dd[k]);
            c2[k]  = 2.0f * c;
            sp[k]  = 0.0f;
            sc[k]  = s;
        }

        f32x2 acc[E_PER][3];
        #pragma unroll
        for (int k = 0; k < E_PER; k++) {
            #pragma unroll
            for (int c = 0; c < 3; c++) { acc[k][c].x = 0.f; acc[k][c].y = 0.f; }
        }

        // rbf dot: each LDS read (3 x ds_read_b64 per n) feeds 4 edges.
        #pragma unroll
        for (int n = 0; n < NRBF; n++) {
            const float* wp = sm_wr + n * NOUT + 2 * lane;
            const f32x2 w0 = *(const f32x2*)(wp);
            const f32x2 w1 = *(const f32x2*)(wp + 128);
            const f32x2 w2 = *(const f32x2*)(wp + 256);
            #pragma unroll
            for (int k = 0; k < E_PER; k++) {
                acc[k][0] += sc[k] * w0;
                acc[k][1] += sc[k] * w1;
                acc[k][2] += sc[k] * w2;
                const float sn = __builtin_fmaf(c2[k], sc[k], -sp[k]);
                sp[k] = sc[k]; sc[k] = sn;
            }
        }

        #pragma unroll
        for (int k = 0; k < E_PER; k++) {
            const f32x2 w0 = acc[k][0] * uu[k] + brv[0] * env[k];
            const f32x2 w1 = acc[k][1] * uu[k] + brv[1] * env[k];
            const f32x2 w2 = acc[k][2] * uu[k] + brv[2] * env[k];

            const float o0x = bf16lo_to_f(p[k][0]) * w0.x, o0y = bf16hi_to_f(p[k][0]) * w0.y;
            const float o1x = bf16lo_to_f(p[k][1]) * w1.x, o1y = bf16hi_to_f(p[k][1]) * w1.y;
            const float o2x = bf16lo_to_f(p[k][2]) * w2.x, o2y = bf16hi_to_f(p[k][2]) * w2.y;

            if constexpr (BF) {
                uint32_t* op = (uint32_t*)out + (size_t)(e0 + k) * (NOUT / 2) + lane;
                op[0]   = pack2_bf16(o0x, o0y);
                op[64]  = pack2_bf16(o1x, o1y);
                op[128] = pack2_bf16(o2x, o2y);
            } else {
                float* op = (float*)out + (size_t)(e0 + k) * NOUT + 2 * lane;
                f32x2 v0; v0.x = o0x; v0.y = o0y;
                f32x2 v1; v1.x = o1x; v1.y = o1y;
                f32x2 v2; v2.x = o2x; v2.y = o2y;
                *(f32x2*)(op)       = v0;
                *(f32x2*)(op + 128) = v1;
                *(f32x2*)(op + 256) = v2;
            }
        }
    }
}

__global__ __launch_bounds__(256) void k_edge(const void* dist, const int* nbrs,
                                              const void* Wr, const void* brp,
                                              const short* inv, void* out,
                                              int total_waves,
                                              const uint32_t* __restrict__ flag) {
    __shared__ float smem[NRBF * NOUT + NOUT];   // 32,256 B -> LDS allows 4 blocks/CU
    const int t = threadIdx.x;
    const uint32_t fl = *flag;
    if (fl) {
        for (int i = t; i < NRBF * NOUT; i += 256) smem[i] = ldf<true>(Wr, i);
        for (int i = t; i < NOUT; i += 256)        smem[NRBF * NOUT + i] = ldf<true>(brp, i);
    } else {
        for (int i = t; i < NRBF * NOUT; i += 256) smem[i] = ldf<false>(Wr, i);
        for (int i = t; i < NOUT; i += 256)        smem[NRBF * NOUT + i] = ldf<false>(brp, i);
    }
    __syncthreads();
    if (fl) edge_body<true>(dist, nbrs, inv, out, total_waves, smem, smem + NRBF * NOUT);
    else    edge_body<false>(dist, nbrs, inv, out, total_waves, smem, smem + NRBF * NOUT);
}

extern "C" void kernel_launch(void* const* d_in, const int* in_sizes, int n_in,
                              void* d_out, int out_size, void* d_ws, size_t ws_size,
                              hipStream_t stream) {
    const void* s_j  = d_in[0];
    const void* dist = d_in[1];
    const int*  nbrs = (const int*)d_in[2];
    const void* W1   = d_in[3];
    const void* b1   = d_in[4];
    const void* W2   = d_in[5];
    const void* b2   = d_in[6];
    const void* Wr   = d_in[7];
    const void* br   = d_in[8];

    uint32_t* flag = (uint32_t*)d_ws;                       // 4 B (+pad to 256 B)
    short* h   = (short*)d_ws + 128;                        // 20000*128 bf16 = 5.12 MB
    short* inv = h + (size_t)NNODES * FEAT;                 // 20000*384 bf16 = 15.36 MB

    dim3 blk(256);
    k_detect<<<dim3(1), dim3(64), 0, stream>>>((const uint32_t*)s_j, flag);
    k_mlp1<<<dim3(313, FEAT / 16), blk, 0, stream>>>(s_j, W1, b1, h, flag);
    k_mlp2<<<dim3(313, NOUT / 16), blk, 0, stream>>>(h, W2, b2, inv, flag);

    const int blocks = 2048;                                 // 8192 waves
    const int total_waves = blocks * (256 / 64);
    k_edge<<<dim3(blocks), blk, 0, stream>>>(dist, nbrs, Wr, br, inv, d_out,
                                             total_waves, flag);
}